// Round 1
// baseline (466.312 us; speedup 1.0000x reference)
//
#include <hip/hip_runtime.h>
#include <math.h>
#include <stdint.h>
#include <stddef.h>

// ---------- types ----------
typedef short bf16x8 __attribute__((ext_vector_type(8)));   // 8 bf16 (4 VGPRs)
typedef short bf16x4 __attribute__((ext_vector_type(4)));   // 4 bf16 (2 VGPRs)
typedef float f32x4  __attribute__((ext_vector_type(4)));

// problem constants
#define BATCH   8
#define D       1024          // model dim == GEMM K (x-derived part) == N
#define POSD    32
#define WIN     1056          // W row length (D + POSD)
#define MBARS   2048
#define MROWS   16384         // BATCH * MBARS
#define NOUT    1024

// fp32 -> bf16 round-to-nearest-even
__device__ __forceinline__ short f2bf(float f) {
    unsigned u = __builtin_bit_cast(unsigned, f);
    u += 0x7fffu + ((u >> 16) & 1u);
    return (short)(u >> 16);
}

// async global -> LDS, 16B/lane; LDS dest = wave-uniform base + lane*16
__device__ __forceinline__ void async_load16(const short* g, short* l) {
    __builtin_amdgcn_global_load_lds((__attribute__((address_space(1))) void*)g,
                                     (__attribute__((address_space(3))) void*)l,
                                     16, 0, 0);
}

// ---------- kernel 1: tiny prep ----------
// blocks [0,1024): cast W[:, :1024] -> bf16 Wb [1024][1024]
// blocks [1024,1280): FFW[mb][n] = bias[n] + sum_j ff[mb][j] * W[n][1024+j]   (8 mb rows per block)
// FFW folds the fourier columns AND the bias into a per-(mb,n) f32 bias table (batch-independent),
// so the main GEMM runs a clean K=1024 and never materializes ff per row.
__global__ __launch_bounds__(256) void prep2(const float* __restrict__ W,
                                             const float* __restrict__ bias,
                                             short* __restrict__ Wb,
                                             float* __restrict__ FFW) {
    const int t   = threadIdx.x;
    const int bid = blockIdx.x;
    if (bid < NOUT) {
        const float* wr = W + (size_t)bid * WIN;
        float4 v = ((const float4*)wr)[t];                    // cols 0..1023
        bf16x4 o = { f2bf(v.x), f2bf(v.y), f2bf(v.z), f2bf(v.w) };
        *(bf16x4*)(Wb + (size_t)bid * D + t * 4) = o;
    } else {
        const int mb0 = (bid - NOUT) * 8;                     // 8 bar rows per block
        __shared__ float ff[8][32];
        if (t < 32) {
            float fr = expf((float)(t & 15) * (6.907755278982137f / 15.0f)); // linspace(0,ln1000,16)
#pragma unroll
            for (int e = 0; e < 8; ++e) {
                float pos = (float)(mb0 + e) * (1.0f / (float)(MBARS - 1));
                float ang = pos * fr;
                ff[e][t] = (t < 16) ? sinf(ang) : cosf(ang);
            }
        }
        __syncthreads();
#pragma unroll
        for (int u = 0; u < 4; ++u) {
            const int n = t + u * 256;
            const float* wp = W + (size_t)n * WIN + D;        // pos-embed columns of row n
            float4 wv[8];
#pragma unroll
            for (int blk = 0; blk < 8; ++blk) wv[blk] = ((const float4*)wp)[blk];
            const float bn = bias[n];
#pragma unroll
            for (int e = 0; e < 8; ++e) {
                float s = bn;
#pragma unroll
                for (int blk = 0; blk < 8; ++blk) {
                    s += ff[e][blk * 4 + 0] * wv[blk].x + ff[e][blk * 4 + 1] * wv[blk].y
                       + ff[e][blk * 4 + 2] * wv[blk].z + ff[e][blk * 4 + 3] * wv[blk].w;
                }
                FFW[(size_t)(mb0 + e) * NOUT + n] = s;
            }
        }
    }
}

// ---------- kernel 2: fused mean + GEMM ----------
// C[64 bars][1024] per block = mean4(x-rows)@Wb^T + FFW[mb].  Full-N tile so x (256 MB, the
// dominant traffic) is read EXACTLY once.  512 threads = 8 waves, each owning 64x128; BK=64,
// 16 K-steps; LDS = A 8 KB + B 128 KB (single-buffered, proven 2-barrier schedule).
// A is reg-staged (f32 load -> mean -> bf16 -> swizzled ds_write); B streams via global_load_lds
// with the XOR swizzle applied on the pre-swizzled GLOBAL source octet (LDS dest must be linear).
__global__ __launch_bounds__(512, 2) void fused(const float* __restrict__ x,
                                                const short* __restrict__ Wb,
                                                const float* __restrict__ FFW,
                                                float* __restrict__ out) {
    __shared__ short As[64 * 64];      // 8 KB,  swizzled row-major [m][k]
    __shared__ short Bs[1024 * 64];    // 128 KB, swizzled row-major [n][k]

    const int tid  = threadIdx.x;
    const int wave = tid >> 6;          // 0..7
    const int lane = tid & 63;
    const int m0   = blockIdx.x * 64;   // flat bar row (gridDim.x = 256; 2048 % 64 == 0, no batch straddle)

    // staging indices: thread t -> row (t>>3), octet (t&7); swizzle slot j of row r holds octet j^(r&7)
    const int ra = tid >> 3;            // 0..63
    const int oa = tid & 7;
    const float* xg = x + (size_t)(m0 + ra) * 4096 + oa * 8;        // bar ra: 4 beat rows x 1024 f32
    short* aw = As + ra * 64 + ((oa ^ (ra & 7)) << 3);              // swizzled ds_write slot
    const short* bg = Wb + (size_t)ra * D + ((oa ^ (ra & 7)) << 3); // pre-swizzled global source
    short* bl = Bs + wave * 512;                                    // linear dest; HW adds lane*16B

    // fragment decode (16x16x32 bf16)
    const int r  = lane & 15;
    const int q  = lane >> 4;
    const int rx = r & 7;
    const short* afr = As + r * 64;
    const short* bfr = Bs + (wave * 128 + r) * 64;
    const int sl0 = ((q    ) ^ rx) << 3;   // s=0: k-octets 0..3
    const int sl1 = ((4 + q) ^ rx) << 3;   // s=1: k-octets 4..7

    f32x4 acc[4][8] = {};

    for (int k0 = 0; k0 < D; k0 += 64) {   // 16 iterations
        __syncthreads();
        // A: issue 8 f32x4 loads first (HBM latency starts early)
        float4 t00 = *(const float4*)(xg + k0);
        float4 t01 = *(const float4*)(xg + k0 + 4);
        float4 t10 = *(const float4*)(xg + k0 + 1024);
        float4 t11 = *(const float4*)(xg + k0 + 1028);
        float4 t20 = *(const float4*)(xg + k0 + 2048);
        float4 t21 = *(const float4*)(xg + k0 + 2052);
        float4 t30 = *(const float4*)(xg + k0 + 3072);
        float4 t31 = *(const float4*)(xg + k0 + 3076);
        // B: 16 issues x 8 KB = 128 KB (L2-resident Wb)
#pragma unroll
        for (int i = 0; i < 16; ++i)
            async_load16(bg + k0 + (size_t)i * 64 * D, bl + i * 4096);
        // segment mean -> bf16 -> swizzled LDS
        bf16x8 av = { f2bf((t00.x + t10.x + t20.x + t30.x) * 0.25f),
                      f2bf((t00.y + t10.y + t20.y + t30.y) * 0.25f),
                      f2bf((t00.z + t10.z + t20.z + t30.z) * 0.25f),
                      f2bf((t00.w + t10.w + t20.w + t30.w) * 0.25f),
                      f2bf((t01.x + t11.x + t21.x + t31.x) * 0.25f),
                      f2bf((t01.y + t11.y + t21.y + t31.y) * 0.25f),
                      f2bf((t01.z + t11.z + t21.z + t31.z) * 0.25f),
                      f2bf((t01.w + t11.w + t21.w + t31.w) * 0.25f) };
        *(bf16x8*)aw = av;
        __syncthreads();   // drains ds_write (lgkm) + global_load_lds (vmcnt)

#pragma unroll
        for (int s = 0; s < 2; ++s) {
            const int sl = s ? sl1 : sl0;
            bf16x8 a[4], b[8];
#pragma unroll
            for (int i = 0; i < 4; ++i) a[i] = *(const bf16x8*)(afr + i * 1024 + sl);
#pragma unroll
            for (int j = 0; j < 8; ++j) b[j] = *(const bf16x8*)(bfr + j * 1024 + sl);
#pragma unroll
            for (int i = 0; i < 4; ++i)
#pragma unroll
                for (int j = 0; j < 8; ++j)
                    acc[i][j] = __builtin_amdgcn_mfma_f32_16x16x32_bf16(a[i], b[j], acc[i][j], 0, 0, 0);
        }
    }

    // epilogue: C/D layout col = lane&15, row = (lane>>4)*4 + reg; add FFW[mb][n] (bias folded in)
    const int mbb = m0 & (MBARS - 1);
    const int c0  = wave * 128 + r;
    const int rt0 = q << 2;
#pragma unroll
    for (int i = 0; i < 4; ++i)
#pragma unroll
        for (int rg = 0; rg < 4; ++rg) {
            const int rt = i * 16 + rt0 + rg;
            const float* fw = FFW + (size_t)(mbb + rt) * NOUT + c0;
            float* cp = out + (size_t)(m0 + rt) * NOUT + c0;
#pragma unroll
            for (int j = 0; j < 8; ++j)
                cp[j * 16] = acc[i][j][rg] + fw[j * 16];
        }
}

extern "C" void kernel_launch(void* const* d_in, const int* in_sizes, int n_in,
                              void* d_out, int out_size, void* d_ws, size_t ws_size,
                              hipStream_t stream) {
    const float* x    = (const float*)d_in[0];   // [8, 8192, 1024]
    const float* W    = (const float*)d_in[1];   // [1024, 1056]
    const float* bias = (const float*)d_in[2];   // [1024]
    float* out = (float*)d_out;                  // [8, 2048, 1024]

    // workspace: Wb bf16 [1024][1024] (2 MB) then FFW f32 [2048][1024] (8 MB)
    short* Wb  = (short*)d_ws;
    float* FFW = (float*)((char*)d_ws + (size_t)NOUT * D * sizeof(short));

    prep2<<<dim3(NOUT + MBARS / 8), dim3(256), 0, stream>>>(W, bias, Wb, FFW);
    fused<<<dim3(MROWS / 64), dim3(512), 0, stream>>>(x, Wb, FFW, out);
}